// Round 17
// baseline (135.874 us; speedup 1.0000x reference)
//
#include <hip/hip_runtime.h>

#define BB   16
#define NN   4096
#define MM   1024
#define CIN  256
#define CSK  128
#define COUT 256
#define KCH  384              // CIN + CSK
#define NP   65536            // BB * NN
#define NSEG2 512             // gemm1 p-blocks = stats segments
#define NCHUNK 8
#define MCH  (MM / NCHUNK)    // 128
#define CVB  32               // interp channel-slots per block

typedef __attribute__((ext_vector_type(8))) short bf16x8;
typedef __attribute__((ext_vector_type(4))) float f32x4;
typedef __attribute__((ext_vector_type(8))) unsigned short ushort8v;
typedef __attribute__((ext_vector_type(4))) unsigned short ushort4v;

static __device__ __forceinline__ unsigned short f2bf(float f) {
    unsigned u = __builtin_bit_cast(unsigned, f);
    u += 0x7fffu + ((u >> 16) & 1u);          // round-to-nearest-even
    return (unsigned short)(u >> 16);
}
static __device__ __forceinline__ float bf2f(unsigned short h) {
    unsigned u = ((unsigned)h) << 16;
    return __builtin_bit_cast(float, u);
}

// exact 11-op sorted-insert of (d, m) into ((D0,I0)<=(D1,I1)<=(D2,I2));
// strict-< compares == reference top_k stable tie order. Pure fp32.
#define KSELP(D0, D1, D2, I0, I1, I2, d, m) do {                            \
    unsigned long long cc0, cc1, cc2;                                       \
    asm("v_cmp_lt_f32 %[c0], %[vd], %[vd0]\n\t"                             \
        "v_cmp_lt_f32 %[c1], %[vd], %[vd1]\n\t"                             \
        "v_cmp_lt_f32 %[c2], %[vd], %[vd2]\n\t"                             \
        "v_cndmask_b32 %[vi2], %[vi2], %[vm], %[c2]\n\t"                    \
        "v_cndmask_b32 %[vi2], %[vi2], %[vi1], %[c1]\n\t"                   \
        "v_cndmask_b32 %[vi1], %[vi1], %[vm], %[c1]\n\t"                    \
        "v_cndmask_b32 %[vi1], %[vi1], %[vi0], %[c0]\n\t"                   \
        "v_cndmask_b32 %[vi0], %[vi0], %[vm], %[c0]\n\t"                    \
        "v_med3_f32 %[vd2], %[vd], %[vd1], %[vd2]\n\t"                      \
        "v_med3_f32 %[vd1], %[vd], %[vd0], %[vd1]\n\t"                      \
        "v_min_f32 %[vd0], %[vd0], %[vd]"                                   \
        : [vd0]"+v"(D0), [vd1]"+v"(D1), [vd2]"+v"(D2),                      \
          [vi0]"+v"(I0), [vi1]"+v"(I1), [vi2]"+v"(I2),                      \
          [c0]"=&s"(cc0), [c1]"=&s"(cc1), [c2]"=&s"(cc2)                    \
        : [vd]"v"(d), [vm]"v"(m));                                          \
} while (0)

// ---------------------------------------------------------------------------
// K0 megakernel, knn = 4 points/thread (1024 pts x 128 centroids per block):
//   blk 0..511     : knn partial
//   blk 512..2559  : cf fp32 -> bf16
//   blk 2560..4607 : pf transpose -> HbT
//   blk 4608..5247 : W1/W2 -> bf16
// First dispatch round (2048 block slots) = 512 knn + 1536 cf co-resident.
// ---------------------------------------------------------------------------
__global__ __launch_bounds__(256) void megak_kernel(
    const float* __restrict__ pts, const float* __restrict__ cen,
    float* __restrict__ pdist, int* __restrict__ pidx,
    const float* __restrict__ cf, unsigned short* __restrict__ cfb,
    const float* __restrict__ pf, unsigned short* __restrict__ HbT,
    const float* __restrict__ W1, const float* __restrict__ W2,
    unsigned short* __restrict__ W1b, unsigned short* __restrict__ W2b)
{
    __shared__ union { float scw[MCH]; float ls[64][65]; } su;
    int blk = blockIdx.x;
    int t = threadIdx.x;

    if (blk < 512) {
        // ---------------- KNN partial: 4 points/thread, quad select state
        int g     = blk;
        int p0    = (g >> 3) * 1024;
        int chunk = g & 7;
        int b     = p0 >> 12;
        int m0    = chunk * MCH;
        const float* cb = cen + (size_t)b * 3 * MM + 3 * m0;
        if (t < MCH) {
            float x = cb[3*t], y = cb[3*t+1], z = cb[3*t+2];
            su.scw[t] = x*x + y*y + z*z;
        }
        __syncthreads();

        const float* pb = pts + (size_t)b * 3 * NN;
        float px[4], py[4], pz[4], pw[4];
        #pragma unroll
        for (int q = 0; q < 4; ++q) {
            int n = (p0 + q * 256 + t) & (NN - 1);
            px[q] = pb[3*n]; py[q] = pb[3*n+1]; pz[q] = pb[3*n+2];
            pw[q] = px[q]*px[q] + py[q]*py[q] + pz[q]*pz[q];
        }

        float D0a=1e30f, D1a=1e30f, D2a=1e30f; int I0a=0, I1a=0, I2a=0;
        float D0b=1e30f, D1b=1e30f, D2b=1e30f; int I0b=0, I1b=0, I2b=0;
        float D0c=1e30f, D1c=1e30f, D2c=1e30f; int I0c=0, I1c=0, I2c=0;
        float D0d=1e30f, D1d=1e30f, D2d=1e30f; int I0d=0, I1d=0, I2d=0;
        #pragma unroll 4
        for (int m = 0; m < MCH; ++m) {
            float cx = cb[3*m], cy = cb[3*m+1], cz = cb[3*m+2]; // uniform -> s_load
            float cw = su.scw[m];                               // ds_read_b32 bcast
            float dA = (pw[0] + cw) - 2.0f * (px[0]*cx + py[0]*cy + pz[0]*cz);
            float dB = (pw[1] + cw) - 2.0f * (px[1]*cx + py[1]*cy + pz[1]*cz);
            float dC = (pw[2] + cw) - 2.0f * (px[2]*cx + py[2]*cy + pz[2]*cz);
            float dD = (pw[3] + cw) - 2.0f * (px[3]*cx + py[3]*cy + pz[3]*cz);
            KSELP(D0a, D1a, D2a, I0a, I1a, I2a, dA, m);
            KSELP(D0b, D1b, D2b, I0b, I1b, I2b, dB, m);
            KSELP(D0c, D1c, D2c, I0c, I1c, I2c, dC, m);
            KSELP(D0d, D1d, D2d, I0d, I1d, I2d, dD, m);
        }
        int ba = ((p0 + t) * NCHUNK + chunk) * 3;
        int bb_ = ((p0 + 256 + t) * NCHUNK + chunk) * 3;
        int bc = ((p0 + 512 + t) * NCHUNK + chunk) * 3;
        int bd = ((p0 + 768 + t) * NCHUNK + chunk) * 3;
        pdist[ba]  = D0a; pdist[ba+1]  = D1a; pdist[ba+2]  = D2a;
        pidx[ba]   = m0+I0a; pidx[ba+1]  = m0+I1a; pidx[ba+2]  = m0+I2a;
        pdist[bb_] = D0b; pdist[bb_+1] = D1b; pdist[bb_+2] = D2b;
        pidx[bb_]  = m0+I0b; pidx[bb_+1] = m0+I1b; pidx[bb_+2] = m0+I2b;
        pdist[bc]  = D0c; pdist[bc+1]  = D1c; pdist[bc+2]  = D2c;
        pidx[bc]   = m0+I0c; pidx[bc+1]  = m0+I1c; pidx[bc+2]  = m0+I2c;
        pdist[bd]  = D0d; pdist[bd+1]  = D1d; pdist[bd+2]  = D2d;
        pidx[bd]   = m0+I0d; pidx[bd+1]  = m0+I1d; pidx[bd+2]  = m0+I2d;
        return;
    }
    if (blk < 2560) {
        // ---------------- cf -> bf16
        int g = blk - 512;
        size_t e8 = ((size_t)g * 256 + t) * 8;
        const float4* cf4 = (const float4*)(cf + e8);
        float4 a = cf4[0], b4 = cf4[1];
        ushort8v w;
        w[0]=f2bf(a.x); w[1]=f2bf(a.y); w[2]=f2bf(a.z); w[3]=f2bf(a.w);
        w[4]=f2bf(b4.x); w[5]=f2bf(b4.y); w[6]=f2bf(b4.z); w[7]=f2bf(b4.w);
        *(ushort8v*)&cfb[e8] = w;
        return;
    }
    if (blk < 4608) {
        // ---------------- pf transpose: 64 n x 64 c tile
        int g = blk - 2560;
        int b = g >> 7;
        int r = g & 127;
        int n0 = (r >> 1) * 64;
        int c0 = (r & 1) * 64;
        const float* src = pf + (size_t)b * CSK * NN;
        #pragma unroll
        for (int i = 0; i < 16; ++i) {
            int id = t + i * 256;
            int cc = id >> 6, nn = id & 63;
            su.ls[nn][cc] = src[(size_t)(c0 + cc) * NN + n0 + nn];
        }
        __syncthreads();
        int row = t & 63, ch0 = (t >> 6) * 16;
        unsigned short* dst = HbT + ((size_t)b * NN + n0 + row) * KCH + c0 + ch0;
        #pragma unroll
        for (int g2 = 0; g2 < 2; ++g2) {
            ushort8v w;
            #pragma unroll
            for (int j = 0; j < 8; ++j) w[j] = f2bf(su.ls[row][ch0 + g2*8 + j]);
            *(ushort8v*)&dst[g2*8] = w;
        }
        return;
    }
    {
        int i = (blk - 4608) * 256 + t;
        if (i < COUT * KCH) W1b[i] = f2bf(W1[i]);
        else {
            int j = i - COUT * KCH;
            if (j < COUT * COUT) W2b[j] = f2bf(W2[j]);
        }
    }
}

// ---------------------------------------------------------------------------
// K1: interp + inline KNN-merge + scramble (unchanged R14/R16).
// ---------------------------------------------------------------------------
__global__ __launch_bounds__(256) void interp_kernel(
    const unsigned short* __restrict__ cfb, const float* __restrict__ pdist,
    const int* __restrict__ pidx, unsigned short* __restrict__ HbT)
{
    __shared__ int   li[CVB][3];
    __shared__ float lw[CVB][3];
    __shared__ unsigned short tile[CVB][258];
    int xcd = blockIdx.x & 7;
    int j   = blockIdx.x >> 3;
    int b   = xcd * 2 + (j >> 7);
    int rem = j & 127;
    int hi  = rem >> 3;
    int ch  = rem & 7;
    int t = threadIdx.x;
    if (t < CVB) {
        int P = b * NN + (ch * CVB + t) * 16 + hi;
        float d0 = 1e30f, d1 = 1e30f, d2v = 1e30f;
        int   i0 = 0, i1 = 0, i2 = 0;
        int base = P * NCHUNK * 3;
        #pragma unroll
        for (int c = 0; c < NCHUNK * 3; ++c) {
            float d = pdist[base + c];
            int   i = pidx[base + c];
            bool c2 = d < d2v, c1 = d < d1, c0 = d < d0;
            d2v = c1 ? d1 : (c2 ? d : d2v);
            i2  = c1 ? i1 : (c2 ? i : i2);
            d1  = c0 ? d0 : (c1 ? d : d1);
            i1  = c0 ? i0 : (c1 ? i : i1);
            d0  = c0 ? d  : d0;
            i0  = c0 ? i  : i0;
        }
        float w0 = 1.0f / fmaxf(d0,  1e-16f);
        float w1 = 1.0f / fmaxf(d1,  1e-16f);
        float w2 = 1.0f / fmaxf(d2v, 1e-16f);
        float inv = 1.0f / (w0 + w1 + w2);
        li[t][0] = i0;     li[t][1] = i1;     li[t][2] = i2;
        lw[t][0] = w0*inv; lw[t][1] = w1*inv; lw[t][2] = w2*inv;
    }
    __syncthreads();
    const unsigned short* cfbb = cfb + (size_t)b * MM * CIN;
    #pragma unroll 4
    for (int cv = 0; cv < CVB; ++cv) {
        float v = lw[cv][0] * bf2f(cfbb[(size_t)li[cv][0] * CIN + t])
                + lw[cv][1] * bf2f(cfbb[(size_t)li[cv][1] * CIN + t])
                + lw[cv][2] * bf2f(cfbb[(size_t)li[cv][2] * CIN + t]);
        tile[cv][t] = f2bf(v);
    }
    __syncthreads();
    size_t dstbase = ((size_t)b * NN + hi * 256 + t) * KCH + CSK + ch * CVB;
    #pragma unroll
    for (int g = 0; g < CVB / 8; ++g) {
        ushort8v w;
        #pragma unroll
        for (int j2 = 0; j2 < 8; ++j2) w[j2] = tile[g*8 + j2][t];
        *(ushort8v*)&HbT[dstbase + g*8] = w;
    }
}

// ---------------------------------------------------------------------------
// K2: GEMM1 (unchanged R14: gload_lds dbuf + swizzle + XCD-paired decode).
// ---------------------------------------------------------------------------
#define SWZ(r) (((r) >> 1) & 3)
#define GLL(g, l) __builtin_amdgcn_global_load_lds(                          \
    (const __attribute__((address_space(1))) unsigned int*)(g),              \
    (__attribute__((address_space(3))) unsigned int*)(l), 16, 0, 0)

__global__ __launch_bounds__(256) void gemm1_kernel(
    const unsigned short* __restrict__ HbT, const unsigned short* __restrict__ W1b,
    const float* __restrict__ b1, unsigned short* __restrict__ h1T,
    float* __restrict__ psum, float* __restrict__ psq)
{
    __shared__ union {
        struct {
            __align__(16) unsigned short A[2][128 * 32];   // linear, swizzled content
            __align__(16) unsigned short B[2][128 * 32];
        } s;
        struct {
            __align__(16) unsigned short eps[64][136];
            float red[512];
        } e;
    } u;
    int bid = blockIdx.x;
    int segx = (bid >> 4) * 8 + (bid & 7);    // 0..511 : p-tile / stats segment
    int yy   = (bid >> 3) & 1;                // o-half
    int pp0 = segx * 128;
    int o0  = yy * 128;
    int t = threadIdx.x;
    int wv = t >> 6, L = t & 63;
    int wr = wv >> 1, wc = wv & 1;
    int lr = L & 15, lk = L >> 4;

    const unsigned short* gA[2];
    const unsigned short* gB[2];
    int ldso[2];
    #pragma unroll
    for (int j = 0; j < 2; ++j) {
        int row = wv*32 + j*16 + (L >> 2);
        int sg  = (L & 3) ^ SWZ(row);
        gA[j] = W1b + (size_t)(o0 + row) * KCH + sg*8;
        gB[j] = HbT + (size_t)(pp0 + row) * KCH + sg*8;
        ldso[j] = wv*1024 + j*512;
    }
    int offA[4], offB[4];
    #pragma unroll
    for (int m = 0; m < 4; ++m) {
        int ar = wr*64 + m*16 + lr;
        offA[m] = ar*32 + (lk ^ SWZ(ar))*8;
    }
    #pragma unroll
    for (int n = 0; n < 4; ++n) {
        int br = wc*64 + n*16 + lr;
        offB[n] = br*32 + (lk ^ SWZ(br))*8;
    }

    f32x4 acc[4][4] = {};

    #pragma unroll
    for (int j = 0; j < 2; ++j) {
        GLL(gA[j], &u.s.A[0][ldso[j]]);
        GLL(gB[j], &u.s.B[0][ldso[j]]);
    }
    __syncthreads();

    for (int ks = 0; ks < KCH / 32; ++ks) {
        int cur = ks & 1;
        if (ks + 1 < KCH / 32) {
            #pragma unroll
            for (int j = 0; j < 2; ++j) {
                GLL(gA[j] + (ks + 1) * 32, &u.s.A[cur ^ 1][ldso[j]]);
                GLL(gB[j] + (ks + 1) * 32, &u.s.B[cur ^ 1][ldso[j]]);
            }
        }
        bf16x8 af[4], bfr[4];
        #pragma unroll
        for (int m = 0; m < 4; ++m) af[m] = *(const bf16x8*)&u.s.A[cur][offA[m]];
        #pragma unroll
        for (int n = 0; n < 4; ++n) bfr[n] = *(const bf16x8*)&u.s.B[cur][offB[n]];
        #pragma unroll
        for (int m = 0; m < 4; ++m)
            #pragma unroll
            for (int n = 0; n < 4; ++n)
                acc[m][n] = __builtin_amdgcn_mfma_f32_16x16x32_bf16(af[m], bfr[n], acc[m][n], 0, 0, 0);
        __syncthreads();
    }

    float bb[4][4];
    #pragma unroll
    for (int m = 0; m < 4; ++m)
        #pragma unroll
        for (int j = 0; j < 4; ++j)
            bb[m][j] = b1[o0 + wr*64 + m*16 + lk*4 + j];
    float sprt[4][4] = {{0.f}}, qprt[4][4] = {{0.f}};
    #pragma unroll
    for (int pw = 0; pw < 2; ++pw) {
        if (wc == pw) {
            #pragma unroll
            for (int n = 0; n < 4; ++n) {
                int r = n*16 + lr;
                #pragma unroll
                for (int m = 0; m < 4; ++m) {
                    f32x4 v = acc[m][n];
                    ushort4v w;
                    #pragma unroll
                    for (int j = 0; j < 4; ++j) {
                        float f = v[j] + bb[m][j];
                        w[j] = f2bf(f);
                        float rr = bf2f(w[j]);
                        sprt[m][j] += rr;
                        qprt[m][j] = fmaf(rr, rr, qprt[m][j]);
                    }
                    *(ushort4v*)&u.e.eps[r][wr*64 + m*16 + lk*4] = w;
                }
            }
        }
        __syncthreads();
        {
            int r = t >> 2, seg = t & 3;
            size_t gbase = ((size_t)(pp0 + pw*64 + r)) * COUT + o0 + seg * 32;
            #pragma unroll
            for (int k = 0; k < 4; ++k) {
                ushort8v vv = *(const ushort8v*)&u.e.eps[r][seg*32 + k*8];
                *(ushort8v*)&h1T[gbase + k*8] = vv;
            }
        }
        __syncthreads();
    }
    #pragma unroll
    for (int m = 0; m < 4; ++m)
        #pragma unroll
        for (int j = 0; j < 4; ++j) {
            float s = sprt[m][j], q = qprt[m][j];
            #pragma unroll
            for (int off = 1; off < 16; off <<= 1) {
                s += __shfl_xor(s, off, 64);
                q += __shfl_xor(q, off, 64);
            }
            sprt[m][j] = s; qprt[m][j] = q;
        }
    if (lr == 0) {
        #pragma unroll
        for (int m = 0; m < 4; ++m)
            #pragma unroll
            for (int j = 0; j < 4; ++j) {
                int ol = wr*64 + m*16 + lk*4 + j;
                u.e.red[wc*128 + ol]       = sprt[m][j];
                u.e.red[256 + wc*128 + ol] = qprt[m][j];
            }
    }
    __syncthreads();
    if (t < 128) {
        float S = u.e.red[t] + u.e.red[128 + t];
        float Q = u.e.red[256 + t] + u.e.red[384 + t];
        psum[(size_t)(o0 + t) * NSEG2 + segx] = S;
        psq [(size_t)(o0 + t) * NSEG2 + segx] = Q;
    }
}

// ---------------------------------------------------------------------------
// K3: BN finalize (unchanged).
// ---------------------------------------------------------------------------
__global__ __launch_bounds__(256) void bnfin_kernel(
    const float* __restrict__ psum, const float* __restrict__ psq,
    const float* __restrict__ gamma, const float* __restrict__ beta,
    float* __restrict__ bnscale, float* __restrict__ bnshift)
{
    __shared__ float rs[256], rq[256];
    int o = blockIdx.x, t = threadIdx.x;
    rs[t] = psum[(size_t)o * NSEG2 + t] + psum[(size_t)o * NSEG2 + 256 + t];
    rq[t] = psq [(size_t)o * NSEG2 + t] + psq [(size_t)o * NSEG2 + 256 + t];
    __syncthreads();
    for (int off = 128; off > 0; off >>= 1) {
        if (t < off) { rs[t] += rs[t + off]; rq[t] += rq[t + off]; }
        __syncthreads();
    }
    if (t == 0) {
        float mean = rs[0] * (1.0f / NP);
        float var  = rq[0] * (1.0f / NP) - mean * mean;
        float sc = gamma[o] * rsqrtf(var + 1e-5f);
        bnscale[o] = sc;
        bnshift[o] = fmaf(-mean, sc, beta[o]);
    }
}

// ---------------------------------------------------------------------------
// K4: GEMM2 (unchanged R14: XCD-paired decode).
// ---------------------------------------------------------------------------
__global__ __launch_bounds__(256) void gemm2_kernel(
    const unsigned short* __restrict__ h1T, const unsigned short* __restrict__ W2b,
    const float* __restrict__ b2, const float* __restrict__ bnscale,
    const float* __restrict__ bnshift, float* __restrict__ out)
{
    __shared__ union {
        struct {
            __align__(16) unsigned short As[128][40];
            __align__(16) unsigned short Bs[128][40];
        } s;
        float eps[64][132];
    } u;
    __shared__ float scs[COUT], shs[COUT];
    int bid = blockIdx.x;
    int pp0 = ((bid >> 4) * 8 + (bid & 7)) * 128;
    int o0  = ((bid >> 3) & 1) * 128;
    int t = threadIdx.x;
    scs[t] = bnscale[t]; shs[t] = bnshift[t];
    int wid = t >> 6, lane = t & 63;
    int wr = wid >> 1, wc = wid & 1;
    int lr = lane & 15, lk = lane >> 4;

    int rowi[2], qi[2];
    ushort8v ra[2], rb[2];
    #pragma unroll
    for (int i = 0; i < 2; ++i) { int id = t + i*256; rowi[i] = id >> 2; qi[i] = id & 3; }
    #pragma unroll
    for (int i = 0; i < 2; ++i) {
        ra[i] = *(const ushort8v*)&W2b[(size_t)(o0 + rowi[i]) * COUT + qi[i]*8];
        rb[i] = *(const ushort8v*)&h1T[(size_t)(pp0 + rowi[i]) * COUT + qi[i]*8];
    }
    f32x4 acc[4][4] = {};
    __syncthreads();

    for (int c0 = 0; c0 < COUT; c0 += 32) {
        #pragma unroll
        for (int i = 0; i < 2; ++i) {
            *(ushort8v*)&u.s.As[rowi[i]][qi[i]*8] = ra[i];
            ushort8v bv;
            #pragma unroll
            for (int j = 0; j < 8; ++j) {
                float f = fmaf(bf2f(rb[i][j]), scs[c0 + qi[i]*8 + j], shs[c0 + qi[i]*8 + j]);
                bv[j] = f2bf(fmaxf(f, 0.0f));
            }
            *(ushort8v*)&u.s.Bs[rowi[i]][qi[i]*8] = bv;
        }
        __syncthreads();
        int cn = (c0 + 32 < COUT) ? c0 + 32 : c0;
        #pragma unroll
        for (int i = 0; i < 2; ++i) {
            ra[i] = *(const ushort8v*)&W2b[(size_t)(o0 + rowi[i]) * COUT + cn + qi[i]*8];
            rb[i] = *(const ushort8v*)&h1T[(size_t)(pp0 + rowi[i]) * COUT + cn + qi[i]*8];
        }
        bf16x8 af[4], bfr[4];
        #pragma unroll
        for (int m = 0; m < 4; ++m) af[m] = *(const bf16x8*)&u.s.As[wr*64 + m*16 + lr][lk*8];
        #pragma unroll
        for (int n = 0; n < 4; ++n) bfr[n] = *(const bf16x8*)&u.s.Bs[wc*64 + n*16 + lr][lk*8];
        #pragma unroll
        for (int m = 0; m < 4; ++m)
            #pragma unroll
            for (int n = 0; n < 4; ++n)
                acc[m][n] = __builtin_amdgcn_mfma_f32_16x16x32_bf16(af[m], bfr[n], acc[m][n], 0, 0, 0);
        __syncthreads();
    }
    int b  = pp0 >> 12;
    int n0 = pp0 & (NN - 1);
    float b2v[4][4];
    #pragma unroll
    for (int m = 0; m < 4; ++m)
        #pragma unroll
        for (int j = 0; j < 4; ++j)
            b2v[m][j] = b2[o0 + wr*64 + m*16 + lk*4 + j];
    #pragma unroll
    for (int ow = 0; ow < 2; ++ow) {
        if (wr == ow) {
            #pragma unroll
            for (int m = 0; m < 4; ++m)
                #pragma unroll
                for (int n = 0; n < 4; ++n) {
                    f32x4 v = acc[m][n];
                    int pl = wc*64 + n*16 + lr;
                    #pragma unroll
                    for (int j = 0; j < 4; ++j)
                        u.eps[m*16 + lk*4 + j][pl] = v[j] + b2v[m][j];
                }
        }
        __syncthreads();
        #pragma unroll
        for (int i = 0; i < 8; ++i) {
            int r  = (t >> 5) + i * 8;
            int c4 = (t & 31) * 4;
            float4 v = *(const float4*)&u.eps[r][c4];
            *(float4*)&out[((size_t)(b * COUT + o0 + ow*64 + r)) * NN + n0 + c4] = v;
        }
        __syncthreads();
    }
}

// ---------------------------------------------------------------------------
extern "C" void kernel_launch(void* const* d_in, const int* in_sizes, int n_in,
                              void* d_out, int out_size, void* d_ws, size_t ws_size,
                              hipStream_t stream)
{
    const float* pts   = (const float*)d_in[0];
    const float* pf    = (const float*)d_in[1];
    const float* cen   = (const float*)d_in[2];
    const float* cf    = (const float*)d_in[3];
    const float* W1    = (const float*)d_in[4];
    const float* b1    = (const float*)d_in[5];
    const float* gamma = (const float*)d_in[6];
    const float* beta  = (const float*)d_in[7];
    const float* W2    = (const float*)d_in[8];
    const float* b2    = (const float*)d_in[9];
    float* out = (float*)d_out;

    char* ws = (char*)d_ws;
    size_t off = 0;
    unsigned short* HbT = (unsigned short*)(ws + off); off += (size_t)NP * KCH * 2;
    unsigned short* h1T = (unsigned short*)(ws + off); off += (size_t)NP * COUT * 2;
    unsigned short* W1b = (unsigned short*)(ws + off); off += (size_t)COUT * KCH * 2;
    unsigned short* W2b = (unsigned short*)(ws + off); off += (size_t)COUT * COUT * 2;
    unsigned short* cfb = (unsigned short*)(ws + off); off += (size_t)BB * MM * CIN * 2;
    float* pdist   = (float*)(ws + off); off += (size_t)NP * NCHUNK * 3 * sizeof(float);
    int*   pidx    = (int*)(ws + off);   off += (size_t)NP * NCHUNK * 3 * sizeof(int);
    float* psum    = (float*)(ws + off); off += (size_t)COUT * NSEG2 * sizeof(float);
    float* psq     = (float*)(ws + off); off += (size_t)COUT * NSEG2 * sizeof(float);
    float* bnscale = (float*)(ws + off); off += 1024;
    float* bnshift = (float*)(ws + off); off += 1024;
    (void)ws_size; (void)in_sizes; (void)n_in; (void)out_size;

    hipLaunchKernelGGL(megak_kernel,  dim3(5248),  dim3(256), 0, stream,
                       pts, cen, pdist, pidx, cf, cfb, pf, HbT, W1, W2, W1b, W2b);
    hipLaunchKernelGGL(interp_kernel, dim3(2048),  dim3(256), 0, stream,
                       cfb, pdist, pidx, HbT);
    hipLaunchKernelGGL(gemm1_kernel,  dim3(1024),  dim3(256), 0, stream,
                       HbT, W1b, b1, h1T, psum, psq);
    hipLaunchKernelGGL(bnfin_kernel,  dim3(COUT),  dim3(256), 0, stream,
                       psum, psq, gamma, beta, bnscale, bnshift);
    hipLaunchKernelGGL(gemm2_kernel,  dim3(1024),  dim3(256), 0, stream,
                       h1T, W2b, b2, bnscale, bnshift, out);
}

// Round 18
// 125.953 us; speedup vs baseline: 1.0788x; 1.0788x over previous
//
#include <hip/hip_runtime.h>

#define BB   16
#define NN   4096
#define MM   1024
#define CIN  256
#define CSK  128
#define COUT 256
#define KCH  384              // CIN + CSK
#define NP   65536            // BB * NN
#define NSEG2 512             // gemm1 p-blocks = stats segments
#define NCHUNK 8
#define MCH  (MM / NCHUNK)    // 128
#define CVB  32               // interp channel-slots per block

typedef __attribute__((ext_vector_type(8))) short bf16x8;
typedef __attribute__((ext_vector_type(4))) float f32x4;
typedef __attribute__((ext_vector_type(8))) unsigned short ushort8v;
typedef __attribute__((ext_vector_type(4))) unsigned short ushort4v;

static __device__ __forceinline__ unsigned short f2bf(float f) {
    unsigned u = __builtin_bit_cast(unsigned, f);
    u += 0x7fffu + ((u >> 16) & 1u);          // round-to-nearest-even
    return (unsigned short)(u >> 16);
}
static __device__ __forceinline__ float bf2f(unsigned short h) {
    unsigned u = ((unsigned)h) << 16;
    return __builtin_bit_cast(float, u);
}

// exact 11-op sorted-insert of (d, m) into ((d0,i0)<=(d1,i1)<=(d2,i2));
// strict-< compares == reference top_k stable tie order. Pure fp32.
#define KSEL(d, m) do {                                                     \
    unsigned long long cc0, cc1, cc2;                                       \
    asm("v_cmp_lt_f32 %[c0], %[vd], %[vd0]\n\t"                             \
        "v_cmp_lt_f32 %[c1], %[vd], %[vd1]\n\t"                             \
        "v_cmp_lt_f32 %[c2], %[vd], %[vd2]\n\t"                             \
        "v_cndmask_b32 %[vi2], %[vi2], %[vm], %[c2]\n\t"                    \
        "v_cndmask_b32 %[vi2], %[vi2], %[vi1], %[c1]\n\t"                   \
        "v_cndmask_b32 %[vi1], %[vi1], %[vm], %[c1]\n\t"                    \
        "v_cndmask_b32 %[vi1], %[vi1], %[vi0], %[c0]\n\t"                   \
        "v_cndmask_b32 %[vi0], %[vi0], %[vm], %[c0]\n\t"                    \
        "v_med3_f32 %[vd2], %[vd], %[vd1], %[vd2]\n\t"                      \
        "v_med3_f32 %[vd1], %[vd], %[vd0], %[vd1]\n\t"                      \
        "v_min_f32 %[vd0], %[vd0], %[vd]"                                   \
        : [vd0]"+v"(d0), [vd1]"+v"(d1), [vd2]"+v"(d2v),                     \
          [vi0]"+v"(i0), [vi1]"+v"(i1), [vi2]"+v"(i2),                      \
          [c0]"=&s"(cc0), [c1]"=&s"(cc1), [c2]"=&s"(cc2)                    \
        : [vd]"v"(d), [vm]"v"(m));                                          \
} while (0)

// ---------------------------------------------------------------------------
// K0 megakernel (R11 structure): knn partials (0..2047) | cf->bf16
// (2048..4095) | pf transpose (4096..6143) | W->bf16 (6144..6783)
// ---------------------------------------------------------------------------
__global__ __launch_bounds__(256) void megak_kernel(
    const float* __restrict__ pts, const float* __restrict__ cen,
    float* __restrict__ pdist, int* __restrict__ pidx,
    const float* __restrict__ cf, unsigned short* __restrict__ cfb,
    const float* __restrict__ pf, unsigned short* __restrict__ HbT,
    const float* __restrict__ W1, const float* __restrict__ W2,
    unsigned short* __restrict__ W1b, unsigned short* __restrict__ W2b)
{
    __shared__ union { float scw[MCH]; float ls[64][65]; } su;
    int blk = blockIdx.x;
    int t = threadIdx.x;

    if (blk < 2048) {
        int p0    = (blk >> 3) * 256;
        int chunk = blk & 7;
        int b     = p0 >> 12;
        int m0    = chunk * MCH;
        const float* cb = cen + (size_t)b * 3 * MM + 3 * m0;
        if (t < MCH) {
            float x = cb[3*t], y = cb[3*t+1], z = cb[3*t+2];
            su.scw[t] = x*x + y*y + z*z;
        }
        __syncthreads();

        int p = p0 + t;
        int n = p & (NN - 1);
        const float* pb = pts + (size_t)b * 3 * NN;
        float px = pb[3*n], py = pb[3*n+1], pz = pb[3*n+2];
        float pw = px*px + py*py + pz*pz;

        float d0 = 1e30f, d1 = 1e30f, d2v = 1e30f;
        int   i0 = 0, i1 = 0, i2 = 0;
        #pragma unroll 8
        for (int m = 0; m < MCH; ++m) {
            float cx = cb[3*m], cy = cb[3*m+1], cz = cb[3*m+2]; // uniform -> s_load
            float cw = su.scw[m];                               // ds_read_b32 bcast
            float dot = px*cx + py*cy + pz*cz;
            float d = (pw + cw) - 2.0f * dot;   // same expansion as reference
            KSEL(d, m);
        }
        int base = (p * NCHUNK + chunk) * 3;
        pdist[base] = d0;      pdist[base+1] = d1;      pdist[base+2] = d2v;
        pidx[base]  = m0 + i0; pidx[base+1]  = m0 + i1; pidx[base+2]  = m0 + i2;
        return;
    }
    if (blk < 4096) {
        int g = blk - 2048;
        size_t e8 = ((size_t)g * 256 + t) * 8;
        const float4* cf4 = (const float4*)(cf + e8);
        float4 a = cf4[0], b4 = cf4[1];
        ushort8v w;
        w[0]=f2bf(a.x); w[1]=f2bf(a.y); w[2]=f2bf(a.z); w[3]=f2bf(a.w);
        w[4]=f2bf(b4.x); w[5]=f2bf(b4.y); w[6]=f2bf(b4.z); w[7]=f2bf(b4.w);
        *(ushort8v*)&cfb[e8] = w;
        return;
    }
    if (blk < 6144) {
        int g = blk - 4096;
        int b = g >> 7;
        int r = g & 127;
        int n0 = (r >> 1) * 64;
        int c0 = (r & 1) * 64;
        const float* src = pf + (size_t)b * CSK * NN;
        #pragma unroll
        for (int i = 0; i < 16; ++i) {
            int id = t + i * 256;
            int cc = id >> 6, nn = id & 63;
            su.ls[nn][cc] = src[(size_t)(c0 + cc) * NN + n0 + nn];
        }
        __syncthreads();
        int row = t & 63, ch0 = (t >> 6) * 16;
        unsigned short* dst = HbT + ((size_t)b * NN + n0 + row) * KCH + c0 + ch0;
        #pragma unroll
        for (int g2 = 0; g2 < 2; ++g2) {
            ushort8v w;
            #pragma unroll
            for (int j = 0; j < 8; ++j) w[j] = f2bf(su.ls[row][ch0 + g2*8 + j]);
            *(ushort8v*)&dst[g2*8] = w;
        }
        return;
    }
    {
        int i = (blk - 6144) * 256 + t;
        if (i < COUT * KCH) W1b[i] = f2bf(W1[i]);
        else {
            int j = i - COUT * KCH;
            if (j < COUT * COUT) W2b[j] = f2bf(W2[j]);
        }
    }
}

// ---------------------------------------------------------------------------
// K1: interp + inline KNN-merge + scramble.
// ---------------------------------------------------------------------------
__global__ __launch_bounds__(256) void interp_kernel(
    const unsigned short* __restrict__ cfb, const float* __restrict__ pdist,
    const int* __restrict__ pidx, unsigned short* __restrict__ HbT)
{
    __shared__ int   li[CVB][3];
    __shared__ float lw[CVB][3];
    __shared__ unsigned short tile[CVB][258];
    int xcd = blockIdx.x & 7;
    int j   = blockIdx.x >> 3;
    int b   = xcd * 2 + (j >> 7);
    int rem = j & 127;
    int hi  = rem >> 3;
    int ch  = rem & 7;
    int t = threadIdx.x;
    if (t < CVB) {
        int P = b * NN + (ch * CVB + t) * 16 + hi;
        float d0 = 1e30f, d1 = 1e30f, d2v = 1e30f;
        int   i0 = 0, i1 = 0, i2 = 0;
        int base = P * NCHUNK * 3;
        #pragma unroll
        for (int c = 0; c < NCHUNK * 3; ++c) {
            float d = pdist[base + c];
            int   i = pidx[base + c];
            bool c2 = d < d2v, c1 = d < d1, c0 = d < d0;
            d2v = c1 ? d1 : (c2 ? d : d2v);
            i2  = c1 ? i1 : (c2 ? i : i2);
            d1  = c0 ? d0 : (c1 ? d : d1);
            i1  = c0 ? i0 : (c1 ? i : i1);
            d0  = c0 ? d  : d0;
            i0  = c0 ? i  : i0;
        }
        float w0 = 1.0f / fmaxf(d0,  1e-16f);
        float w1 = 1.0f / fmaxf(d1,  1e-16f);
        float w2 = 1.0f / fmaxf(d2v, 1e-16f);
        float inv = 1.0f / (w0 + w1 + w2);
        li[t][0] = i0;     li[t][1] = i1;     li[t][2] = i2;
        lw[t][0] = w0*inv; lw[t][1] = w1*inv; lw[t][2] = w2*inv;
    }
    __syncthreads();
    const unsigned short* cfbb = cfb + (size_t)b * MM * CIN;
    #pragma unroll 4
    for (int cv = 0; cv < CVB; ++cv) {
        float v = lw[cv][0] * bf2f(cfbb[(size_t)li[cv][0] * CIN + t])
                + lw[cv][1] * bf2f(cfbb[(size_t)li[cv][1] * CIN + t])
                + lw[cv][2] * bf2f(cfbb[(size_t)li[cv][2] * CIN + t]);
        tile[cv][t] = f2bf(v);
    }
    __syncthreads();
    size_t dstbase = ((size_t)b * NN + hi * 256 + t) * KCH + CSK + ch * CVB;
    #pragma unroll
    for (int g = 0; g < CVB / 8; ++g) {
        ushort8v w;
        #pragma unroll
        for (int j2 = 0; j2 < 8; ++j2) w[j2] = tile[g*8 + j2][t];
        *(ushort8v*)&HbT[dstbase + g*8] = w;
    }
}

// ---------------------------------------------------------------------------
// K2: GEMM1 — gload_lds dbuf + swizzle + XCD-paired decode.
// ---------------------------------------------------------------------------
#define SWZ(r) (((r) >> 1) & 3)
#define GLL(g, l) __builtin_amdgcn_global_load_lds(                          \
    (const __attribute__((address_space(1))) unsigned int*)(g),              \
    (__attribute__((address_space(3))) unsigned int*)(l), 16, 0, 0)

__global__ __launch_bounds__(256) void gemm1_kernel(
    const unsigned short* __restrict__ HbT, const unsigned short* __restrict__ W1b,
    const float* __restrict__ b1, unsigned short* __restrict__ h1T,
    float* __restrict__ psum, float* __restrict__ psq)
{
    __shared__ union {
        struct {
            __align__(16) unsigned short A[2][128 * 32];   // linear, swizzled content
            __align__(16) unsigned short B[2][128 * 32];
        } s;
        struct {
            __align__(16) unsigned short eps[64][136];
            float red[512];
        } e;
    } u;
    int bid = blockIdx.x;
    int segx = (bid >> 4) * 8 + (bid & 7);    // 0..511 : p-tile / stats segment
    int yy   = (bid >> 3) & 1;                // o-half
    int pp0 = segx * 128;
    int o0  = yy * 128;
    int t = threadIdx.x;
    int wv = t >> 6, L = t & 63;
    int wr = wv >> 1, wc = wv & 1;
    int lr = L & 15, lk = L >> 4;

    const unsigned short* gA[2];
    const unsigned short* gB[2];
    int ldso[2];
    #pragma unroll
    for (int j = 0; j < 2; ++j) {
        int row = wv*32 + j*16 + (L >> 2);
        int sg  = (L & 3) ^ SWZ(row);
        gA[j] = W1b + (size_t)(o0 + row) * KCH + sg*8;
        gB[j] = HbT + (size_t)(pp0 + row) * KCH + sg*8;
        ldso[j] = wv*1024 + j*512;
    }
    int offA[4], offB[4];
    #pragma unroll
    for (int m = 0; m < 4; ++m) {
        int ar = wr*64 + m*16 + lr;
        offA[m] = ar*32 + (lk ^ SWZ(ar))*8;
    }
    #pragma unroll
    for (int n = 0; n < 4; ++n) {
        int br = wc*64 + n*16 + lr;
        offB[n] = br*32 + (lk ^ SWZ(br))*8;
    }

    f32x4 acc[4][4] = {};

    #pragma unroll
    for (int j = 0; j < 2; ++j) {
        GLL(gA[j], &u.s.A[0][ldso[j]]);
        GLL(gB[j], &u.s.B[0][ldso[j]]);
    }
    __syncthreads();

    for (int ks = 0; ks < KCH / 32; ++ks) {
        int cur = ks & 1;
        if (ks + 1 < KCH / 32) {
            #pragma unroll
            for (int j = 0; j < 2; ++j) {
                GLL(gA[j] + (ks + 1) * 32, &u.s.A[cur ^ 1][ldso[j]]);
                GLL(gB[j] + (ks + 1) * 32, &u.s.B[cur ^ 1][ldso[j]]);
            }
        }
        bf16x8 af[4], bfr[4];
        #pragma unroll
        for (int m = 0; m < 4; ++m) af[m] = *(const bf16x8*)&u.s.A[cur][offA[m]];
        #pragma unroll
        for (int n = 0; n < 4; ++n) bfr[n] = *(const bf16x8*)&u.s.B[cur][offB[n]];
        #pragma unroll
        for (int m = 0; m < 4; ++m)
            #pragma unroll
            for (int n = 0; n < 4; ++n)
                acc[m][n] = __builtin_amdgcn_mfma_f32_16x16x32_bf16(af[m], bfr[n], acc[m][n], 0, 0, 0);
        __syncthreads();
    }

    float bb[4][4];
    #pragma unroll
    for (int m = 0; m < 4; ++m)
        #pragma unroll
        for (int j = 0; j < 4; ++j)
            bb[m][j] = b1[o0 + wr*64 + m*16 + lk*4 + j];
    float sprt[4][4] = {{0.f}}, qprt[4][4] = {{0.f}};
    #pragma unroll
    for (int pw = 0; pw < 2; ++pw) {
        if (wc == pw) {
            #pragma unroll
            for (int n = 0; n < 4; ++n) {
                int r = n*16 + lr;
                #pragma unroll
                for (int m = 0; m < 4; ++m) {
                    f32x4 v = acc[m][n];
                    ushort4v w;
                    #pragma unroll
                    for (int j = 0; j < 4; ++j) {
                        float f = v[j] + bb[m][j];
                        w[j] = f2bf(f);
                        float rr = bf2f(w[j]);
                        sprt[m][j] += rr;
                        qprt[m][j] = fmaf(rr, rr, qprt[m][j]);
                    }
                    *(ushort4v*)&u.e.eps[r][wr*64 + m*16 + lk*4] = w;
                }
            }
        }
        __syncthreads();
        {
            int r = t >> 2, seg = t & 3;
            size_t gbase = ((size_t)(pp0 + pw*64 + r)) * COUT + o0 + seg * 32;
            #pragma unroll
            for (int k = 0; k < 4; ++k) {
                ushort8v vv = *(const ushort8v*)&u.e.eps[r][seg*32 + k*8];
                *(ushort8v*)&h1T[gbase + k*8] = vv;
            }
        }
        __syncthreads();
    }
    #pragma unroll
    for (int m = 0; m < 4; ++m)
        #pragma unroll
        for (int j = 0; j < 4; ++j) {
            float s = sprt[m][j], q = qprt[m][j];
            #pragma unroll
            for (int off = 1; off < 16; off <<= 1) {
                s += __shfl_xor(s, off, 64);
                q += __shfl_xor(q, off, 64);
            }
            sprt[m][j] = s; qprt[m][j] = q;
        }
    if (lr == 0) {
        #pragma unroll
        for (int m = 0; m < 4; ++m)
            #pragma unroll
            for (int j = 0; j < 4; ++j) {
                int ol = wr*64 + m*16 + lk*4 + j;
                u.e.red[wc*128 + ol]       = sprt[m][j];
                u.e.red[256 + wc*128 + ol] = qprt[m][j];
            }
    }
    __syncthreads();
    if (t < 128) {
        float S = u.e.red[t] + u.e.red[128 + t];
        float Q = u.e.red[256 + t] + u.e.red[384 + t];
        psum[(size_t)(o0 + t) * NSEG2 + segx] = S;
        psq [(size_t)(o0 + t) * NSEG2 + segx] = Q;
    }
}

// ---------------------------------------------------------------------------
// K3: BN finalize.
// ---------------------------------------------------------------------------
__global__ __launch_bounds__(256) void bnfin_kernel(
    const float* __restrict__ psum, const float* __restrict__ psq,
    const float* __restrict__ gamma, const float* __restrict__ beta,
    float* __restrict__ bnscale, float* __restrict__ bnshift)
{
    __shared__ float rs[256], rq[256];
    int o = blockIdx.x, t = threadIdx.x;
    rs[t] = psum[(size_t)o * NSEG2 + t] + psum[(size_t)o * NSEG2 + 256 + t];
    rq[t] = psq [(size_t)o * NSEG2 + t] + psq [(size_t)o * NSEG2 + 256 + t];
    __syncthreads();
    for (int off = 128; off > 0; off >>= 1) {
        if (t < off) { rs[t] += rs[t + off]; rq[t] += rq[t + off]; }
        __syncthreads();
    }
    if (t == 0) {
        float mean = rs[0] * (1.0f / NP);
        float var  = rq[0] * (1.0f / NP) - mean * mean;
        float sc = gamma[o] * rsqrtf(var + 1e-5f);
        bnscale[o] = sc;
        bnshift[o] = fmaf(-mean, sc, beta[o]);
    }
}

// ---------------------------------------------------------------------------
// K4: GEMM2 — XCD-paired decode, BN+ReLU at LDS-write, reg-prefetch,
// transposed epilogue.
// ---------------------------------------------------------------------------
__global__ __launch_bounds__(256) void gemm2_kernel(
    const unsigned short* __restrict__ h1T, const unsigned short* __restrict__ W2b,
    const float* __restrict__ b2, const float* __restrict__ bnscale,
    const float* __restrict__ bnshift, float* __restrict__ out)
{
    __shared__ union {
        struct {
            __align__(16) unsigned short As[128][40];
            __align__(16) unsigned short Bs[128][40];
        } s;
        float eps[64][132];
    } u;
    __shared__ float scs[COUT], shs[COUT];
    int bid = blockIdx.x;
    int pp0 = ((bid >> 4) * 8 + (bid & 7)) * 128;
    int o0  = ((bid >> 3) & 1) * 128;
    int t = threadIdx.x;
    scs[t] = bnscale[t]; shs[t] = bnshift[t];
    int wid = t >> 6, lane = t & 63;
    int wr = wid >> 1, wc = wid & 1;
    int lr = lane & 15, lk = lane >> 4;

    int rowi[2], qi[2];
    ushort8v ra[2], rb[2];
    #pragma unroll
    for (int i = 0; i < 2; ++i) { int id = t + i*256; rowi[i] = id >> 2; qi[i] = id & 3; }
    #pragma unroll
    for (int i = 0; i < 2; ++i) {
        ra[i] = *(const ushort8v*)&W2b[(size_t)(o0 + rowi[i]) * COUT + qi[i]*8];
        rb[i] = *(const ushort8v*)&h1T[(size_t)(pp0 + rowi[i]) * COUT + qi[i]*8];
    }
    f32x4 acc[4][4] = {};
    __syncthreads();

    for (int c0 = 0; c0 < COUT; c0 += 32) {
        #pragma unroll
        for (int i = 0; i < 2; ++i) {
            *(ushort8v*)&u.s.As[rowi[i]][qi[i]*8] = ra[i];
            ushort8v bv;
            #pragma unroll
            for (int j = 0; j < 8; ++j) {
                float f = fmaf(bf2f(rb[i][j]), scs[c0 + qi[i]*8 + j], shs[c0 + qi[i]*8 + j]);
                bv[j] = f2bf(fmaxf(f, 0.0f));
            }
            *(ushort8v*)&u.s.Bs[rowi[i]][qi[i]*8] = bv;
        }
        __syncthreads();
        int cn = (c0 + 32 < COUT) ? c0 + 32 : c0;
        #pragma unroll
        for (int i = 0; i < 2; ++i) {
            ra[i] = *(const ushort8v*)&W2b[(size_t)(o0 + rowi[i]) * COUT + cn + qi[i]*8];
            rb[i] = *(const ushort8v*)&h1T[(size_t)(pp0 + rowi[i]) * COUT + cn + qi[i]*8];
        }
        bf16x8 af[4], bfr[4];
        #pragma unroll
        for (int m = 0; m < 4; ++m) af[m] = *(const bf16x8*)&u.s.As[wr*64 + m*16 + lr][lk*8];
        #pragma unroll
        for (int n = 0; n < 4; ++n) bfr[n] = *(const bf16x8*)&u.s.Bs[wc*64 + n*16 + lr][lk*8];
        #pragma unroll
        for (int m = 0; m < 4; ++m)
            #pragma unroll
            for (int n = 0; n < 4; ++n)
                acc[m][n] = __builtin_amdgcn_mfma_f32_16x16x32_bf16(af[m], bfr[n], acc[m][n], 0, 0, 0);
        __syncthreads();
    }
    int b  = pp0 >> 12;
    int n0 = pp0 & (NN - 1);
    float b2v[4][4];
    #pragma unroll
    for (int m = 0; m < 4; ++m)
        #pragma unroll
        for (int j = 0; j < 4; ++j)
            b2v[m][j] = b2[o0 + wr*64 + m*16 + lk*4 + j];
    #pragma unroll
    for (int ow = 0; ow < 2; ++ow) {
        if (wr == ow) {
            #pragma unroll
            for (int m = 0; m < 4; ++m)
                #pragma unroll
                for (int n = 0; n < 4; ++n) {
                    f32x4 v = acc[m][n];
                    int pl = wc*64 + n*16 + lr;
                    #pragma unroll
                    for (int j = 0; j < 4; ++j)
                        u.eps[m*16 + lk*4 + j][pl] = v[j] + b2v[m][j];
                }
        }
        __syncthreads();
        #pragma unroll
        for (int i = 0; i < 8; ++i) {
            int r  = (t >> 5) + i * 8;
            int c4 = (t & 31) * 4;
            float4 v = *(const float4*)&u.eps[r][c4];
            *(float4*)&out[((size_t)(b * COUT + o0 + ow*64 + r)) * NN + n0 + c4] = v;
        }
        __syncthreads();
    }
}

// ---------------------------------------------------------------------------
extern "C" void kernel_launch(void* const* d_in, const int* in_sizes, int n_in,
                              void* d_out, int out_size, void* d_ws, size_t ws_size,
                              hipStream_t stream)
{
    const float* pts   = (const float*)d_in[0];
    const float* pf    = (const float*)d_in[1];
    const float* cen   = (const float*)d_in[2];
    const float* cf    = (const float*)d_in[3];
    const float* W1    = (const float*)d_in[4];
    const float* b1    = (const float*)d_in[5];
    const float* gamma = (const float*)d_in[6];
    const float* beta  = (const float*)d_in[7];
    const float* W2    = (const float*)d_in[8];
    const float* b2    = (const float*)d_in[9];
    float* out = (float*)d_out;

    char* ws = (char*)d_ws;
    size_t off = 0;
    unsigned short* HbT = (unsigned short*)(ws + off); off += (size_t)NP * KCH * 2;
    unsigned short* h1T = (unsigned short*)(ws + off); off += (size_t)NP * COUT * 2;
    unsigned short* W1b = (unsigned short*)(ws + off); off += (size_t)COUT * KCH * 2;
    unsigned short* W2b = (unsigned short*)(ws + off); off += (size_t)COUT * COUT * 2;
    unsigned short* cfb = (unsigned short*)(ws + off); off += (size_t)BB * MM * CIN * 2;
    float* pdist   = (float*)(ws + off); off += (size_t)NP * NCHUNK * 3 * sizeof(float);
    int*   pidx    = (int*)(ws + off);   off += (size_t)NP * NCHUNK * 3 * sizeof(int);
    float* psum    = (float*)(ws + off); off += (size_t)COUT * NSEG2 * sizeof(float);
    float* psq     = (float*)(ws + off); off += (size_t)COUT * NSEG2 * sizeof(float);
    float* bnscale = (float*)(ws + off); off += 1024;
    float* bnshift = (float*)(ws + off); off += 1024;
    (void)ws_size; (void)in_sizes; (void)n_in; (void)out_size;

    hipLaunchKernelGGL(megak_kernel,  dim3(6784),  dim3(256), 0, stream,
                       pts, cen, pdist, pidx, cf, cfb, pf, HbT, W1, W2, W1b, W2b);
    hipLaunchKernelGGL(interp_kernel, dim3(2048),  dim3(256), 0, stream,
                       cfb, pdist, pidx, HbT);
    hipLaunchKernelGGL(gemm1_kernel,  dim3(1024),  dim3(256), 0, stream,
                       HbT, W1b, b1, h1T, psum, psq);
    hipLaunchKernelGGL(bnfin_kernel,  dim3(COUT),  dim3(256), 0, stream,
                       psum, psq, gamma, beta, bnscale, bnshift);
    hipLaunchKernelGGL(gemm2_kernel,  dim3(1024),  dim3(256), 0, stream,
                       h1T, W2b, b2, bnscale, bnshift, out);
}